// Round 17
// baseline (4069.323 us; speedup 1.0000x reference)
//
#include <hip/hip_runtime.h>
#include <hip/hip_bf16.h>
#include <cstdint>
#include <cstddef>

#define NWG   256
#define NTH   512
#define LSTEP 1024
#define FAST_TRIES 256

typedef __attribute__((ext_vector_type(8))) short short8;
typedef __attribute__((ext_vector_type(4))) float f32x4;
typedef __attribute__((ext_vector_type(4))) unsigned int u32x4;
typedef __attribute__((ext_vector_type(2))) unsigned int u32x2;

__device__ __forceinline__ unsigned f2bf_bits(float x) {
  __hip_bfloat16 h = __float2bfloat16(x);
  return (unsigned)__builtin_bit_cast(unsigned short, h);
}
__device__ __forceinline__ float bfbits2f(unsigned b) {
  return __bfloat162float(__builtin_bit_cast(__hip_bfloat16, (unsigned short)b));
}
__device__ __forceinline__ float ftanh(float x) {
  const float ax = fminf(fabsf(x), 15.f);
  const float e  = __expf(-2.f * ax);
  const float t  = (1.f - e) / (1.f + e);
  return copysignf(t, x);
}
__device__ __forceinline__ float fsig(float x) {
  const float xx = fmaxf(fminf(x, 30.f), -30.f);
  return 1.f / (1.f + __expf(-xx));
}

// ws: [0,1024) xcctab[wg]=0x100|xcc | [4096..) stateFA,FB,SA,SB (256KB each)
// Exchange protocol == R16 (verified): {pk, tag} u64 entries, tag=S+1,
// parity S&1; F copy = plain stores + nt loads (XCD-L2-local), S copy =
// sc1 via MALL; per-wave physical gate + bounded demotion (no deadlock).
// NEW vs R16 (intra-step restructure only):
//   - phase 2 distributed: wave w owns batch row w (lanes 0-15 = 16 cols)
//   - part_s / ie_part double-buffered by step parity
//   - ONE __syncthreads per step (parity argument: phase2(st-1) reads of
//     parity p precede each wave's sync(st) arrival; phase1(st+1) writes of
//     parity p follow sync(st))
//   - ie_math inside phase 1; u prefetched one step ahead into registers

__global__ void __launch_bounds__(NTH, 2)
fused_scan(const float* __restrict__ u, const float* __restrict__ h0,
           const float* __restrict__ Wi, const float* __restrict__ bi,
           const float* __restrict__ Wm, const float* __restrict__ bm,
           float* __restrict__ out,
           unsigned long long* __restrict__ stateFA,
           unsigned long long* __restrict__ stateFB,
           unsigned long long* __restrict__ stateSA,
           unsigned long long* __restrict__ stateSB,
           unsigned* __restrict__ xcctab)
{
  __shared__ float part_s[2 * 5120];   // [p][kh8][r8][c80] me MFMA partials
  __shared__ float ie_part[2 * 3072];  // [p][kc4][r8][c96] ie MFMA partials
  __shared__ float hf_own[128];        // [r8][j16]
  __shared__ float hs_own[128];
  __shared__ float bm_s[80];
  __shared__ float bi_s[96];

  const int wg   = blockIdx.x;
  const int bc   = wg & 7;         // batch-group: same-XCD under round-robin
  const int jc   = wg >> 3;        // 32 col-groups
  const int j0   = jc * 16;
  const int r0   = bc * 8;
  const int tid  = threadIdx.x;
  const int w    = tid >> 6;
  const int lane = tid & 63;
  const int colf = lane & 15;
  const int ksub = lane >> 4;
  const int rloc = lane & 7;

  // ---- publish my physical XCD id (hint table) ----
  unsigned my_xcc;
  asm volatile("s_getreg_b32 %0, hwreg(HW_REG_XCC_ID)" : "=s"(my_xcc));
  my_xcc &= 0xffu;
  if (tid == 0) {
    unsigned* tp = xcctab + wg;
    const unsigned v = 0x100u | my_xcc;
    asm volatile("global_store_dword %0, %1, off sc1" :: "v"(tp), "v"(v) : "memory");
  }

  // ---- one-time small LDS ----
  if (tid < 80) bm_s[tid] = bm[(tid % 5) * 512 + j0 + tid / 5];
  if (tid >= 128 && tid < 224) {
    const int c = tid - 128;
    bi_s[c] = bi[(c % 6) * 512 + j0 + c / 6];
  }
  // ---- init own hf/hs, publish State(0) with tag=1 (both copies) ----
  if (tid < 128) {
    const int r = tid >> 4, j16 = tid & 15;
    const float f = h0[(size_t)(r0 + r) * 512 + j0 + j16];
    const float s = h0[(size_t)32768 + (size_t)(r0 + r) * 512 + j0 + j16];
    hf_own[tid] = f;
    hs_own[tid] = s;
    const unsigned hb = f2bf_bits(f);
    const unsigned lb = f2bf_bits(f - bfbits2f(hb));
    u32x2 pr; pr[0] = hb | (lb << 16); pr[1] = 1u;
    const size_t eo = (size_t)(r0 + r) * 512 + j0 + j16;
    asm volatile("global_store_dwordx2 %0, %1, off"     :: "v"(stateFA + eo), "v"(pr) : "memory");
    asm volatile("global_store_dwordx2 %0, %1, off sc1" :: "v"(stateSA + eo), "v"(pr) : "memory");
  }

  // ---- per-wave locality gate: are my 4 producers on my XCD? ----
  bool fastmode;
  {
    unsigned pv = 0x100u | my_xcc;   // lanes >= 4: trivially equal
    if (lane < 4) {
      const unsigned* tp = xcctab + bc + (w * 4 + lane) * 8;
      for (;;) {
        unsigned v;
        asm volatile("global_load_dword %0, %1, off sc1" : "=&v"(v) : "v"(tp) : "memory");
        asm volatile("s_waitcnt vmcnt(0)" ::: "memory");
        __builtin_amdgcn_sched_barrier(0);
        if (v & 0x100u) { pv = v; break; }
        __builtin_amdgcn_s_sleep(1);
      }
    }
    fastmode = __all((pv & 0xffu) == my_xcc);
  }

  // ---- B-fragment gathers ----
  short8 bh[5][2], bl[5][2];
  #pragma unroll
  for (int nt = 0; nt < 5; ++nt) {
    const int c = nt * 16 + colf;
    const int gcol = (c % 5) * 512 + j0 + c / 5;
    #pragma unroll
    for (int kt = 0; kt < 2; ++kt) {
      #pragma unroll
      for (int j = 0; j < 8; ++j) {
        const int kg = w * 64 + kt * 32 + ksub * 8 + j;
        const float wv = Wm[(size_t)kg * 2560 + gcol];
        const unsigned hb = f2bf_bits(wv);
        bh[nt][kt][j] = (short)hb;
        bl[nt][kt][j] = (short)f2bf_bits(wv - bfbits2f(hb));
      }
    }
  }
  const int iekc = w & 3;
  const int ienh = w >> 2;
  short8 bih[3], bil[3];
  #pragma unroll
  for (int nt = 0; nt < 3; ++nt) {
    const int c = (ienh * 3 + nt) * 16 + colf;
    const int gcol = (c % 6) * 512 + j0 + c / 6;
    #pragma unroll
    for (int j = 0; j < 8; ++j) {
      const int kg = iekc * 32 + ksub * 8 + j;
      const float wv = Wi[(size_t)kg * 3072 + gcol];
      const unsigned hb = f2bf_bits(wv);
      bih[nt][j] = (short)hb;
      bil[nt][j] = (short)f2bf_bits(wv - bfbits2f(hb));
    }
  }

  const float* ubase = u + (size_t)(r0 + rloc) * 131072 + iekc * 32 + ksub * 8;

  // ---- ie math from prefetched registers into parity buffer ----
  auto ie_math = [&](float* iep, float4 xa_, float4 xb_) {
    const float xv[8] = {xa_.x, xa_.y, xa_.z, xa_.w, xb_.x, xb_.y, xb_.z, xb_.w};
    short8 ah, al;
    #pragma unroll
    for (int j = 0; j < 8; ++j) {
      const unsigned hb = f2bf_bits(xv[j]);
      ah[j] = (short)hb;
      al[j] = (short)f2bf_bits(xv[j] - bfbits2f(hb));
    }
    f32x4 acc[3];
    #pragma unroll
    for (int nt = 0; nt < 3; ++nt) { acc[nt][0]=0.f; acc[nt][1]=0.f; acc[nt][2]=0.f; acc[nt][3]=0.f; }
    #pragma unroll
    for (int nt = 0; nt < 3; ++nt) {
      acc[nt] = __builtin_amdgcn_mfma_f32_16x16x32_bf16(ah, bih[nt], acc[nt], 0, 0, 0);
      acc[nt] = __builtin_amdgcn_mfma_f32_16x16x32_bf16(ah, bil[nt], acc[nt], 0, 0, 0);
      acc[nt] = __builtin_amdgcn_mfma_f32_16x16x32_bf16(al, bih[nt], acc[nt], 0, 0, 0);
    }
    if (lane < 32) {
      const int rb = (lane >> 4) * 4;
      #pragma unroll
      for (int nt = 0; nt < 3; ++nt)
        #pragma unroll
        for (int i = 0; i < 4; ++i)
          iep[iekc * 768 + (rb + i) * 96 + (ienh * 3 + nt) * 16 + colf] = acc[nt][i];
    }
  };

  const bool active = (lane & 8) == 0;   // fragment rows 8-15 are padding
  // u(0) prefetch
  float4 xa = *(const float4*)ubase;
  float4 xb = *(const float4*)(ubase + 4);

  for (int st = 0; st < LSTEP; ++st) {
    const int pbit = st & 1;
    const unsigned long long* __restrict__ scurF = pbit ? stateFB : stateFA;
    unsigned long long* __restrict__ snxtF       = pbit ? stateFA : stateFB;
    const unsigned long long* __restrict__ scurS = pbit ? stateSB : stateSA;
    unsigned long long* __restrict__ snxtS       = pbit ? stateSA : stateSB;
    float* psp = part_s  + pbit * 5120;
    float* iep = ie_part + pbit * 3072;

    // ======== phase 1: dual-path poll-with-payload, unpack, MFMA, ie ========
    {
      const unsigned tag = (unsigned)(st + 1);
      const size_t eoff = (size_t)(r0 + rloc) * 512 + w * 64 + ksub * 8;
      u32x4 p0 = {0,0,0,0}, p1 = {0,0,0,0}, p2 = {0,0,0,0}, p3 = {0,0,0,0};
      u32x4 p4 = {0,0,0,0}, p5 = {0,0,0,0}, p6 = {0,0,0,0}, p7 = {0,0,0,0};
      if (active) {
#define READ8(PTR, FLAG, OKVAR)                                                                              \
        {                                                                                                    \
          asm volatile("global_load_dwordx4 %0, %1, off " FLAG            : "=&v"(p0) : "v"(PTR) : "memory"); \
          asm volatile("global_load_dwordx4 %0, %1, off offset:16 " FLAG  : "=&v"(p1) : "v"(PTR) : "memory"); \
          asm volatile("global_load_dwordx4 %0, %1, off offset:32 " FLAG  : "=&v"(p2) : "v"(PTR) : "memory"); \
          asm volatile("global_load_dwordx4 %0, %1, off offset:48 " FLAG  : "=&v"(p3) : "v"(PTR) : "memory"); \
          asm volatile("global_load_dwordx4 %0, %1, off offset:256 " FLAG : "=&v"(p4) : "v"(PTR) : "memory"); \
          asm volatile("global_load_dwordx4 %0, %1, off offset:272 " FLAG : "=&v"(p5) : "v"(PTR) : "memory"); \
          asm volatile("global_load_dwordx4 %0, %1, off offset:288 " FLAG : "=&v"(p6) : "v"(PTR) : "memory"); \
          asm volatile("global_load_dwordx4 %0, %1, off offset:304 " FLAG : "=&v"(p7) : "v"(PTR) : "memory"); \
          asm volatile("s_waitcnt vmcnt(0)" ::: "memory");                                                   \
          __builtin_amdgcn_sched_barrier(0);  /* rule #18: compare AFTER waitcnt */                          \
          OKVAR = p0[1] >= tag && p0[3] >= tag && p1[1] >= tag && p1[3] >= tag                               \
               && p2[1] >= tag && p2[3] >= tag && p3[1] >= tag && p3[3] >= tag                               \
               && p4[1] >= tag && p4[3] >= tag && p5[1] >= tag && p5[3] >= tag                               \
               && p6[1] >= tag && p6[3] >= tag && p7[1] >= tag && p7[3] >= tag;                              \
        }
        bool got = false;
        if (fastmode) {
          const unsigned long long* baseF = scurF + eoff;
          int tries = 0;
          bool ok;
          do {
            READ8(baseF, "nt", ok)
            if (__all(ok)) { got = true; break; }
          } while (++tries < FAST_TRIES);
          if (!got) fastmode = false;   // deterministic, permanent — no deadlock
        }
        if (!got) {
          const unsigned long long* baseS = scurS + eoff;
          for (;;) {
            bool ok;
            READ8(baseS, "sc1", ok)
            if (__all(ok)) break;
            __builtin_amdgcn_s_sleep(1);
          }
        }
#undef READ8
      }
      __builtin_amdgcn_sched_barrier(0);
      short8 ah[2], al[2];
      ah[0][0] = (short)(p0[0] & 0xffffu); al[0][0] = (short)(p0[0] >> 16);
      ah[0][1] = (short)(p0[2] & 0xffffu); al[0][1] = (short)(p0[2] >> 16);
      ah[0][2] = (short)(p1[0] & 0xffffu); al[0][2] = (short)(p1[0] >> 16);
      ah[0][3] = (short)(p1[2] & 0xffffu); al[0][3] = (short)(p1[2] >> 16);
      ah[0][4] = (short)(p2[0] & 0xffffu); al[0][4] = (short)(p2[0] >> 16);
      ah[0][5] = (short)(p2[2] & 0xffffu); al[0][5] = (short)(p2[2] >> 16);
      ah[0][6] = (short)(p3[0] & 0xffffu); al[0][6] = (short)(p3[0] >> 16);
      ah[0][7] = (short)(p3[2] & 0xffffu); al[0][7] = (short)(p3[2] >> 16);
      ah[1][0] = (short)(p4[0] & 0xffffu); al[1][0] = (short)(p4[0] >> 16);
      ah[1][1] = (short)(p4[2] & 0xffffu); al[1][1] = (short)(p4[2] >> 16);
      ah[1][2] = (short)(p5[0] & 0xffffu); al[1][2] = (short)(p5[0] >> 16);
      ah[1][3] = (short)(p5[2] & 0xffffu); al[1][3] = (short)(p5[2] >> 16);
      ah[1][4] = (short)(p6[0] & 0xffffu); al[1][4] = (short)(p6[0] >> 16);
      ah[1][5] = (short)(p6[2] & 0xffffu); al[1][5] = (short)(p6[2] >> 16);
      ah[1][6] = (short)(p7[0] & 0xffffu); al[1][6] = (short)(p7[0] >> 16);
      ah[1][7] = (short)(p7[2] & 0xffffu); al[1][7] = (short)(p7[2] >> 16);
      f32x4 acc[5];
      #pragma unroll
      for (int nt = 0; nt < 5; ++nt) { acc[nt][0]=0.f; acc[nt][1]=0.f; acc[nt][2]=0.f; acc[nt][3]=0.f; }
      #pragma unroll
      for (int nt = 0; nt < 5; ++nt)
        #pragma unroll
        for (int kt = 0; kt < 2; ++kt) {
          acc[nt] = __builtin_amdgcn_mfma_f32_16x16x32_bf16(ah[kt], bh[nt][kt], acc[nt], 0, 0, 0);
          acc[nt] = __builtin_amdgcn_mfma_f32_16x16x32_bf16(ah[kt], bl[nt][kt], acc[nt], 0, 0, 0);
          acc[nt] = __builtin_amdgcn_mfma_f32_16x16x32_bf16(al[kt], bh[nt][kt], acc[nt], 0, 0, 0);
        }
      if (lane < 32) {
        const int rb = (lane >> 4) * 4;
        #pragma unroll
        for (int nt = 0; nt < 5; ++nt)
          #pragma unroll
          for (int i = 0; i < 4; ++i)
            psp[(w * 8 + rb + i) * 80 + nt * 16 + colf] = acc[nt][i];
      }
    }
    // ---- ie(st) into parity buffer; prefetch u(st+1) ----
    ie_math(iep, xa, xb);
    if (st + 1 < LSTEP) {
      const float* up = ubase + (size_t)(st + 1) * 128;
      xa = *(const float4*)up;
      xb = *(const float4*)(up + 4);
    }
    __syncthreads();   // THE one barrier: part_s/ie_part[pbit] complete

    // ======== phase 2 (distributed): wave w owns batch row w ========
    if (lane < 16) {
      const int j16 = lane;
      float m[5];
      #pragma unroll
      for (int g = 0; g < 5; ++g) {
        float v = bm_s[j16 * 5 + g];
        #pragma unroll
        for (int kh = 0; kh < 8; ++kh) v += psp[kh * 640 + w * 80 + j16 * 5 + g];
        m[g] = v;
      }
      float iacc[6];
      #pragma unroll
      for (int g = 0; g < 6; ++g) {
        float v = bi_s[j16 * 6 + g];
        #pragma unroll
        for (int kc = 0; kc < 4; ++kc) v += iep[kc * 768 + w * 96 + j16 * 6 + g];
        iacc[g] = v;
      }
      const int hidx = w * 16 + j16;
      const float hf = hf_own[hidx];
      const float hs = hs_own[hidx];
      const float a = 1.f + ftanh(iacc[0] + m[0]);
      const float b = 1.5f * (1.f + ftanh(iacc[1] + m[1]));
      const float c = 0.3f + 0.7f * fsig(iacc[2] + m[2]);
      const float d = 0.03f * fsig(iacc[3] + m[3]);
      const float e = 1.f + fsig(iacc[4] + m[4]);
      const float hfn_v = (1.f - c) * hf + c * ftanh(iacc[5] + (a + b * hf * hf - hs) * hf);
      const float eh  = e * hf;
      const float eh2 = eh * eh;
      const float hsn_v = hs * (1.f - d) + d * eh2 * eh2;
      hf_own[hidx] = hfn_v;
      hs_own[hidx] = hsn_v;
      const unsigned hb = f2bf_bits(hfn_v);
      const unsigned lb = f2bf_bits(hfn_v - bfbits2f(hb));
      u32x2 pr; pr[0] = hb | (lb << 16); pr[1] = (unsigned)(st + 2);
      const size_t eo = (size_t)(r0 + w) * 512 + j0 + j16;
      asm volatile("global_store_dwordx2 %0, %1, off"     :: "v"(snxtF + eo), "v"(pr) : "memory");
      asm volatile("global_store_dwordx2 %0, %1, off sc1" :: "v"(snxtS + eo), "v"(pr) : "memory");
      out[(size_t)(r0 + w) * 524288 + (size_t)st * 512 + j0 + j16] = hfn_v;
      if (st == LSTEP - 1)
        out[(size_t)33554432 + (size_t)(r0 + w) * 512 + j0 + j16] = hfn_v;
    }
    // no second barrier: next phase1 writes the OTHER parity; cross-WG
    // consumption is gated by per-entry tags (sibling-wave publishes
    // included — the poll simply spins until they land).
  }
}

extern "C" void kernel_launch(void* const* d_in, const int* in_sizes, int n_in,
                              void* d_out, int out_size, void* d_ws, size_t ws_size,
                              hipStream_t stream) {
  (void)in_sizes; (void)n_in; (void)out_size; (void)ws_size;
  const float* u  = (const float*)d_in[0];
  const float* h0 = (const float*)d_in[1];
  const float* Wi = (const float*)d_in[2];
  const float* bi = (const float*)d_in[3];
  const float* Wm = (const float*)d_in[4];
  const float* bm = (const float*)d_in[5];
  float* out = (float*)d_out;
  unsigned* xcctab = (unsigned*)d_ws;                        // [0, 1024)
  char* sb = (char*)d_ws + 4096;
  unsigned long long* stateFA = (unsigned long long*)(sb);
  unsigned long long* stateFB = (unsigned long long*)(sb + 262144);
  unsigned long long* stateSA = (unsigned long long*)(sb + 2 * 262144);
  unsigned long long* stateSB = (unsigned long long*)(sb + 3 * 262144);
  hipMemsetAsync(d_ws, 0, 4096 + 4 * 262144, stream);  // xcctab + all tags
  hipLaunchKernelGGL(fused_scan, dim3(NWG), dim3(NTH), 0, stream,
                     u, h0, Wi, bi, Wm, bm, out,
                     stateFA, stateFB, stateSA, stateSB, xcctab);
}

// Round 18
// 3448.578 us; speedup vs baseline: 1.1800x; 1.1800x over previous
//
#include <hip/hip_runtime.h>
#include <hip/hip_bf16.h>
#include <cstdint>
#include <cstddef>

#define NWG   256
#define NTH   512
#define LSTEP 1024
#define FAST_TRIES 256

typedef __attribute__((ext_vector_type(8))) short short8;
typedef __attribute__((ext_vector_type(4))) float f32x4;
typedef __attribute__((ext_vector_type(4))) unsigned int u32x4;
typedef __attribute__((ext_vector_type(2))) unsigned int u32x2;

__device__ __forceinline__ unsigned f2bf_bits(float x) {
  __hip_bfloat16 h = __float2bfloat16(x);
  return (unsigned)__builtin_bit_cast(unsigned short, h);
}
__device__ __forceinline__ float bfbits2f(unsigned b) {
  return __bfloat162float(__builtin_bit_cast(__hip_bfloat16, (unsigned short)b));
}
__device__ __forceinline__ float ftanh(float x) {
  const float ax = fminf(fabsf(x), 15.f);
  const float e  = __expf(-2.f * ax);
  const float t  = (1.f - e) / (1.f + e);
  return copysignf(t, x);
}
__device__ __forceinline__ float fsig(float x) {
  const float xx = fmaxf(fminf(x, 30.f), -30.f);
  return 1.f / (1.f + __expf(-xx));
}

// ws: [0,1024) xcctab[wg]=0x100|xcc | [4096..) stateFA,FB,SA,SB (256KB each)
// Exchange protocol == R16 (verified 2901us): {pk, tag} u64 entries,
// tag=S+1, parity S&1; F copy = plain stores + nt loads (XCD-L2-local),
// S copy = sc1 via MALL; per-wave physical gate + bounded demotion.
// ONE change vs R16: phase 2 distributed (wave w owns batch row w,
// lanes 0-15 = 16 cols). Both barriers + post-sync#2 ie_math KEPT —
// R17 showed the post-publish delay is load-bearing for poll timing;
// this cuts producer phase-2 length (publish ~600cy earlier) without
// touching consumer poll start. Reduction order identical => absmax
// must stay byte-identical (8.300781e-3).

__global__ void __launch_bounds__(NTH, 2)
fused_scan(const float* __restrict__ u, const float* __restrict__ h0,
           const float* __restrict__ Wi, const float* __restrict__ bi,
           const float* __restrict__ Wm, const float* __restrict__ bm,
           float* __restrict__ out,
           unsigned long long* __restrict__ stateFA,
           unsigned long long* __restrict__ stateFB,
           unsigned long long* __restrict__ stateSA,
           unsigned long long* __restrict__ stateSB,
           unsigned* __restrict__ xcctab)
{
  __shared__ float part_s[5120];   // [kh8][r8][c80] me MFMA partials
  __shared__ float ie_part[3072];  // [kc4][r8][c96] ie MFMA partials
  __shared__ float hf_own[128];    // [r8][j16]
  __shared__ float hs_own[128];
  __shared__ float bm_s[80];
  __shared__ float bi_s[96];

  const int wg   = blockIdx.x;
  const int bc   = wg & 7;         // batch-group: same-XCD under round-robin
  const int jc   = wg >> 3;        // 32 col-groups
  const int j0   = jc * 16;
  const int r0   = bc * 8;
  const int tid  = threadIdx.x;
  const int w    = tid >> 6;
  const int lane = tid & 63;
  const int colf = lane & 15;
  const int ksub = lane >> 4;
  const int rloc = lane & 7;

  // ---- publish my physical XCD id (hint table) ----
  unsigned my_xcc;
  asm volatile("s_getreg_b32 %0, hwreg(HW_REG_XCC_ID)" : "=s"(my_xcc));
  my_xcc &= 0xffu;
  if (tid == 0) {
    unsigned* tp = xcctab + wg;
    const unsigned v = 0x100u | my_xcc;
    asm volatile("global_store_dword %0, %1, off sc1" :: "v"(tp), "v"(v) : "memory");
  }

  // ---- one-time small LDS ----
  if (tid < 80) bm_s[tid] = bm[(tid % 5) * 512 + j0 + tid / 5];
  if (tid >= 128 && tid < 224) {
    const int c = tid - 128;
    bi_s[c] = bi[(c % 6) * 512 + j0 + c / 6];
  }
  // ---- init own hf/hs, publish State(0) with tag=1 (both copies) ----
  if (tid < 128) {
    const int r = tid >> 4, j16 = tid & 15;
    const float f = h0[(size_t)(r0 + r) * 512 + j0 + j16];
    const float s = h0[(size_t)32768 + (size_t)(r0 + r) * 512 + j0 + j16];
    hf_own[tid] = f;
    hs_own[tid] = s;
    const unsigned hb = f2bf_bits(f);
    const unsigned lb = f2bf_bits(f - bfbits2f(hb));
    u32x2 pr; pr[0] = hb | (lb << 16); pr[1] = 1u;
    const size_t eo = (size_t)(r0 + r) * 512 + j0 + j16;
    asm volatile("global_store_dwordx2 %0, %1, off"     :: "v"(stateFA + eo), "v"(pr) : "memory");
    asm volatile("global_store_dwordx2 %0, %1, off sc1" :: "v"(stateSA + eo), "v"(pr) : "memory");
  }

  // ---- per-wave locality gate: are my 4 producers on my XCD? ----
  bool fastmode;
  {
    unsigned pv = 0x100u | my_xcc;   // lanes >= 4: trivially equal
    if (lane < 4) {
      const unsigned* tp = xcctab + bc + (w * 4 + lane) * 8;
      for (;;) {
        unsigned v;
        asm volatile("global_load_dword %0, %1, off sc1" : "=&v"(v) : "v"(tp) : "memory");
        asm volatile("s_waitcnt vmcnt(0)" ::: "memory");
        __builtin_amdgcn_sched_barrier(0);
        if (v & 0x100u) { pv = v; break; }
        __builtin_amdgcn_s_sleep(1);
      }
    }
    fastmode = __all((pv & 0xffu) == my_xcc);
  }

  // ---- B-fragment gathers ----
  short8 bh[5][2], bl[5][2];
  #pragma unroll
  for (int nt = 0; nt < 5; ++nt) {
    const int c = nt * 16 + colf;
    const int gcol = (c % 5) * 512 + j0 + c / 5;
    #pragma unroll
    for (int kt = 0; kt < 2; ++kt) {
      #pragma unroll
      for (int j = 0; j < 8; ++j) {
        const int kg = w * 64 + kt * 32 + ksub * 8 + j;
        const float wv = Wm[(size_t)kg * 2560 + gcol];
        const unsigned hb = f2bf_bits(wv);
        bh[nt][kt][j] = (short)hb;
        bl[nt][kt][j] = (short)f2bf_bits(wv - bfbits2f(hb));
      }
    }
  }
  const int iekc = w & 3;
  const int ienh = w >> 2;
  short8 bih[3], bil[3];
  #pragma unroll
  for (int nt = 0; nt < 3; ++nt) {
    const int c = (ienh * 3 + nt) * 16 + colf;
    const int gcol = (c % 6) * 512 + j0 + c / 6;
    #pragma unroll
    for (int j = 0; j < 8; ++j) {
      const int kg = iekc * 32 + ksub * 8 + j;
      const float wv = Wi[(size_t)kg * 3072 + gcol];
      const unsigned hb = f2bf_bits(wv);
      bih[nt][j] = (short)hb;
      bil[nt][j] = (short)f2bf_bits(wv - bfbits2f(hb));
    }
  }

  const float* ubase = u + (size_t)(r0 + rloc) * 131072 + iekc * 32 + ksub * 8;

  // ---- ie math from prefetched registers ----
  auto ie_math = [&](float4 xa_, float4 xb_) {
    const float xv[8] = {xa_.x, xa_.y, xa_.z, xa_.w, xb_.x, xb_.y, xb_.z, xb_.w};
    short8 ah, al;
    #pragma unroll
    for (int j = 0; j < 8; ++j) {
      const unsigned hb = f2bf_bits(xv[j]);
      ah[j] = (short)hb;
      al[j] = (short)f2bf_bits(xv[j] - bfbits2f(hb));
    }
    f32x4 acc[3];
    #pragma unroll
    for (int nt = 0; nt < 3; ++nt) { acc[nt][0]=0.f; acc[nt][1]=0.f; acc[nt][2]=0.f; acc[nt][3]=0.f; }
    #pragma unroll
    for (int nt = 0; nt < 3; ++nt) {
      acc[nt] = __builtin_amdgcn_mfma_f32_16x16x32_bf16(ah, bih[nt], acc[nt], 0, 0, 0);
      acc[nt] = __builtin_amdgcn_mfma_f32_16x16x32_bf16(ah, bil[nt], acc[nt], 0, 0, 0);
      acc[nt] = __builtin_amdgcn_mfma_f32_16x16x32_bf16(al, bih[nt], acc[nt], 0, 0, 0);
    }
    if (lane < 32) {
      const int rb = (lane >> 4) * 4;
      #pragma unroll
      for (int nt = 0; nt < 3; ++nt)
        #pragma unroll
        for (int i = 0; i < 4; ++i)
          ie_part[iekc * 768 + (rb + i) * 96 + (ienh * 3 + nt) * 16 + colf] = acc[nt][i];
    }
  };

  // ---- ie(0) ----
  {
    const float4 xa0 = *(const float4*)ubase;
    const float4 xb0 = *(const float4*)(ubase + 4);
    ie_math(xa0, xb0);
  }

  const bool active = (lane & 8) == 0;   // fragment rows 8-15 are padding

  for (int st = 0; st < LSTEP; ++st) {
    const unsigned long long* __restrict__ scurF = (st & 1) ? stateFB : stateFA;
    unsigned long long* __restrict__ snxtF       = (st & 1) ? stateFA : stateFB;
    const unsigned long long* __restrict__ scurS = (st & 1) ? stateSB : stateSA;
    unsigned long long* __restrict__ snxtS       = (st & 1) ? stateSA : stateSB;

    // ======== phase 1: dual-path poll-with-payload, unpack, MFMA ========
    {
      const unsigned tag = (unsigned)(st + 1);
      const size_t eoff = (size_t)(r0 + rloc) * 512 + w * 64 + ksub * 8;
      u32x4 p0 = {0,0,0,0}, p1 = {0,0,0,0}, p2 = {0,0,0,0}, p3 = {0,0,0,0};
      u32x4 p4 = {0,0,0,0}, p5 = {0,0,0,0}, p6 = {0,0,0,0}, p7 = {0,0,0,0};
      if (active) {
#define READ8(PTR, FLAG, OKVAR)                                                                              \
        {                                                                                                    \
          asm volatile("global_load_dwordx4 %0, %1, off " FLAG            : "=&v"(p0) : "v"(PTR) : "memory"); \
          asm volatile("global_load_dwordx4 %0, %1, off offset:16 " FLAG  : "=&v"(p1) : "v"(PTR) : "memory"); \
          asm volatile("global_load_dwordx4 %0, %1, off offset:32 " FLAG  : "=&v"(p2) : "v"(PTR) : "memory"); \
          asm volatile("global_load_dwordx4 %0, %1, off offset:48 " FLAG  : "=&v"(p3) : "v"(PTR) : "memory"); \
          asm volatile("global_load_dwordx4 %0, %1, off offset:256 " FLAG : "=&v"(p4) : "v"(PTR) : "memory"); \
          asm volatile("global_load_dwordx4 %0, %1, off offset:272 " FLAG : "=&v"(p5) : "v"(PTR) : "memory"); \
          asm volatile("global_load_dwordx4 %0, %1, off offset:288 " FLAG : "=&v"(p6) : "v"(PTR) : "memory"); \
          asm volatile("global_load_dwordx4 %0, %1, off offset:304 " FLAG : "=&v"(p7) : "v"(PTR) : "memory"); \
          asm volatile("s_waitcnt vmcnt(0)" ::: "memory");                                                   \
          __builtin_amdgcn_sched_barrier(0);  /* rule #18: compare AFTER waitcnt */                          \
          OKVAR = p0[1] >= tag && p0[3] >= tag && p1[1] >= tag && p1[3] >= tag                               \
               && p2[1] >= tag && p2[3] >= tag && p3[1] >= tag && p3[3] >= tag                               \
               && p4[1] >= tag && p4[3] >= tag && p5[1] >= tag && p5[3] >= tag                               \
               && p6[1] >= tag && p6[3] >= tag && p7[1] >= tag && p7[3] >= tag;                              \
        }
        bool got = false;
        if (fastmode) {
          const unsigned long long* baseF = scurF + eoff;
          int tries = 0;
          bool ok;
          do {
            READ8(baseF, "nt", ok)
            if (__all(ok)) { got = true; break; }
          } while (++tries < FAST_TRIES);
          if (!got) fastmode = false;   // deterministic, permanent — no deadlock
        }
        if (!got) {
          const unsigned long long* baseS = scurS + eoff;
          for (;;) {
            bool ok;
            READ8(baseS, "sc1", ok)
            if (__all(ok)) break;
            __builtin_amdgcn_s_sleep(1);
          }
        }
#undef READ8
      }
      __builtin_amdgcn_sched_barrier(0);
      short8 ah[2], al[2];
      ah[0][0] = (short)(p0[0] & 0xffffu); al[0][0] = (short)(p0[0] >> 16);
      ah[0][1] = (short)(p0[2] & 0xffffu); al[0][1] = (short)(p0[2] >> 16);
      ah[0][2] = (short)(p1[0] & 0xffffu); al[0][2] = (short)(p1[0] >> 16);
      ah[0][3] = (short)(p1[2] & 0xffffu); al[0][3] = (short)(p1[2] >> 16);
      ah[0][4] = (short)(p2[0] & 0xffffu); al[0][4] = (short)(p2[0] >> 16);
      ah[0][5] = (short)(p2[2] & 0xffffu); al[0][5] = (short)(p2[2] >> 16);
      ah[0][6] = (short)(p3[0] & 0xffffu); al[0][6] = (short)(p3[0] >> 16);
      ah[0][7] = (short)(p3[2] & 0xffffu); al[0][7] = (short)(p3[2] >> 16);
      ah[1][0] = (short)(p4[0] & 0xffffu); al[1][0] = (short)(p4[0] >> 16);
      ah[1][1] = (short)(p4[2] & 0xffffu); al[1][1] = (short)(p4[2] >> 16);
      ah[1][2] = (short)(p5[0] & 0xffffu); al[1][2] = (short)(p5[0] >> 16);
      ah[1][3] = (short)(p5[2] & 0xffffu); al[1][3] = (short)(p5[2] >> 16);
      ah[1][4] = (short)(p6[0] & 0xffffu); al[1][4] = (short)(p6[0] >> 16);
      ah[1][5] = (short)(p6[2] & 0xffffu); al[1][5] = (short)(p6[2] >> 16);
      ah[1][6] = (short)(p7[0] & 0xffffu); al[1][6] = (short)(p7[0] >> 16);
      ah[1][7] = (short)(p7[2] & 0xffffu); al[1][7] = (short)(p7[2] >> 16);
      f32x4 acc[5];
      #pragma unroll
      for (int nt = 0; nt < 5; ++nt) { acc[nt][0]=0.f; acc[nt][1]=0.f; acc[nt][2]=0.f; acc[nt][3]=0.f; }
      #pragma unroll
      for (int nt = 0; nt < 5; ++nt)
        #pragma unroll
        for (int kt = 0; kt < 2; ++kt) {
          acc[nt] = __builtin_amdgcn_mfma_f32_16x16x32_bf16(ah[kt], bh[nt][kt], acc[nt], 0, 0, 0);
          acc[nt] = __builtin_amdgcn_mfma_f32_16x16x32_bf16(ah[kt], bl[nt][kt], acc[nt], 0, 0, 0);
          acc[nt] = __builtin_amdgcn_mfma_f32_16x16x32_bf16(al[kt], bh[nt][kt], acc[nt], 0, 0, 0);
        }
      if (lane < 32) {
        const int rb = (lane >> 4) * 4;
        #pragma unroll
        for (int nt = 0; nt < 5; ++nt)
          #pragma unroll
          for (int i = 0; i < 4; ++i)
            part_s[(w * 8 + rb + i) * 80 + nt * 16 + colf] = acc[nt][i];
      }
    }
    __syncthreads();   // sync #1 — part_s/ie_part complete for step st

    // ---- prefetch u(st+1) ----
    float4 xa = {0.f, 0.f, 0.f, 0.f}, xb = {0.f, 0.f, 0.f, 0.f};
    if (st + 1 < LSTEP) {
      const float* up = ubase + (size_t)(st + 1) * 128;
      xa = *(const float4*)up;
      xb = *(const float4*)(up + 4);
    }

    // ======== phase 2 (distributed): wave w owns batch row w ========
    if (lane < 16) {
      const int j16 = lane;
      float m[5];
      #pragma unroll
      for (int g = 0; g < 5; ++g) {
        float v = bm_s[j16 * 5 + g];
        #pragma unroll
        for (int kh = 0; kh < 8; ++kh) v += part_s[kh * 640 + w * 80 + j16 * 5 + g];
        m[g] = v;
      }
      float iacc[6];
      #pragma unroll
      for (int g = 0; g < 6; ++g) {
        float v = bi_s[j16 * 6 + g];
        #pragma unroll
        for (int kc = 0; kc < 4; ++kc) v += ie_part[kc * 768 + w * 96 + j16 * 6 + g];
        iacc[g] = v;
      }
      const int hidx = w * 16 + j16;
      const float hf = hf_own[hidx];
      const float hs = hs_own[hidx];
      const float a = 1.f + ftanh(iacc[0] + m[0]);
      const float b = 1.5f * (1.f + ftanh(iacc[1] + m[1]));
      const float c = 0.3f + 0.7f * fsig(iacc[2] + m[2]);
      const float d = 0.03f * fsig(iacc[3] + m[3]);
      const float e = 1.f + fsig(iacc[4] + m[4]);
      const float hfn_v = (1.f - c) * hf + c * ftanh(iacc[5] + (a + b * hf * hf - hs) * hf);
      const float eh  = e * hf;
      const float eh2 = eh * eh;
      const float hsn_v = hs * (1.f - d) + d * eh2 * eh2;
      hf_own[hidx] = hfn_v;
      hs_own[hidx] = hsn_v;
      const unsigned hb = f2bf_bits(hfn_v);
      const unsigned lb = f2bf_bits(hfn_v - bfbits2f(hb));
      u32x2 pr; pr[0] = hb | (lb << 16); pr[1] = (unsigned)(st + 2);
      const size_t eo = (size_t)(r0 + w) * 512 + j0 + j16;
      asm volatile("global_store_dwordx2 %0, %1, off"     :: "v"(snxtF + eo), "v"(pr) : "memory");
      asm volatile("global_store_dwordx2 %0, %1, off sc1" :: "v"(snxtS + eo), "v"(pr) : "memory");
      out[(size_t)(r0 + w) * 524288 + (size_t)st * 512 + j0 + j16] = hfn_v;
      if (st == LSTEP - 1)
        out[(size_t)33554432 + (size_t)(r0 + w) * 512 + j0 + j16] = hfn_v;
    }
    __syncthreads();   // sync #2 — part_s/ie_part free for reuse
    if (st + 1 < LSTEP) ie_math(xa, xb);  // KEPT: publish->poll delay (R17 lesson)
  }
}

extern "C" void kernel_launch(void* const* d_in, const int* in_sizes, int n_in,
                              void* d_out, int out_size, void* d_ws, size_t ws_size,
                              hipStream_t stream) {
  (void)in_sizes; (void)n_in; (void)out_size; (void)ws_size;
  const float* u  = (const float*)d_in[0];
  const float* h0 = (const float*)d_in[1];
  const float* Wi = (const float*)d_in[2];
  const float* bi = (const float*)d_in[3];
  const float* Wm = (const float*)d_in[4];
  const float* bm = (const float*)d_in[5];
  float* out = (float*)d_out;
  unsigned* xcctab = (unsigned*)d_ws;                        // [0, 1024)
  char* sb = (char*)d_ws + 4096;
  unsigned long long* stateFA = (unsigned long long*)(sb);
  unsigned long long* stateFB = (unsigned long long*)(sb + 262144);
  unsigned long long* stateSA = (unsigned long long*)(sb + 2 * 262144);
  unsigned long long* stateSB = (unsigned long long*)(sb + 3 * 262144);
  hipMemsetAsync(d_ws, 0, 4096 + 4 * 262144, stream);  // xcctab + all tags
  hipLaunchKernelGGL(fused_scan, dim3(NWG), dim3(NTH), 0, stream,
                     u, h0, Wi, bi, Wm, bm, out,
                     stateFA, stateFB, stateSA, stateSB, xcctab);
}

// Round 19
// 2884.229 us; speedup vs baseline: 1.4109x; 1.1957x over previous
//
#include <hip/hip_runtime.h>
#include <hip/hip_bf16.h>
#include <cstdint>
#include <cstddef>

#define NWG   256
#define NTH   512
#define LSTEP 1024
#define FAST_TRIES 4096

typedef __attribute__((ext_vector_type(8))) short short8;
typedef __attribute__((ext_vector_type(4))) float f32x4;
typedef __attribute__((ext_vector_type(4))) unsigned int u32x4;
typedef __attribute__((ext_vector_type(2))) unsigned int u32x2;

__device__ __forceinline__ unsigned f2bf_bits(float x) {
  __hip_bfloat16 h = __float2bfloat16(x);
  return (unsigned)__builtin_bit_cast(unsigned short, h);
}
__device__ __forceinline__ float bfbits2f(unsigned b) {
  return __bfloat162float(__builtin_bit_cast(__hip_bfloat16, (unsigned short)b));
}
__device__ __forceinline__ float ftanh(float x) {
  const float ax = fminf(fabsf(x), 15.f);
  const float e  = __expf(-2.f * ax);
  const float t  = (1.f - e) / (1.f + e);
  return copysignf(t, x);
}
__device__ __forceinline__ float fsig(float x) {
  const float xx = fmaxf(fminf(x, 30.f), -30.f);
  return 1.f / (1.f + __expf(-xx));
}

// ws: [0,1024) xcctab | [1024,2048) flagsF[bc*32+jc] | [4096..) stateFA,FB,SA,SB
// Exchange protocol == R16 (verified 2901us): {pk, tag} u64 entries, tag=S+1,
// parity S&1; F = plain stores + nt loads (XCD-L2-local), S = sc1 via MALL;
// physical gate + bounded demotion.
// ONE change vs R16: fast-path RETRIES poll a 16B flag vector (nt, broadcast,
// 1 L2 access/attempt) instead of re-reading the 4KB payload. R16's payload
// polls demanded ~49 TB/s of L2 BW (> 34.5 ceiling) — congestion inflated
// every RT in the chain. Flags are a HINT (written plain by tid0 after
// sync#2); per-entry tags on the payload remain the only correctness gate.
// Math/order identical => absmax must stay byte-identical (8.300781e-3).

__global__ void __launch_bounds__(NTH, 2)
fused_scan(const float* __restrict__ u, const float* __restrict__ h0,
           const float* __restrict__ Wi, const float* __restrict__ bi,
           const float* __restrict__ Wm, const float* __restrict__ bm,
           float* __restrict__ out,
           unsigned long long* __restrict__ stateFA,
           unsigned long long* __restrict__ stateFB,
           unsigned long long* __restrict__ stateSA,
           unsigned long long* __restrict__ stateSB,
           unsigned* __restrict__ xcctab, unsigned* __restrict__ flagsF)
{
  __shared__ float part_s[5120];   // [kh8][r8][c80] me MFMA partials
  __shared__ float ie_part[3072];  // [kc4][r8][c96] ie MFMA partials
  __shared__ float hf_own[128];    // [r8][j16]
  __shared__ float hs_own[128];
  __shared__ float bm_s[80];
  __shared__ float bi_s[96];

  const int wg   = blockIdx.x;
  const int bc   = wg & 7;         // batch-group: same-XCD under round-robin
  const int jc   = wg >> 3;        // 32 col-groups
  const int j0   = jc * 16;
  const int r0   = bc * 8;
  const int tid  = threadIdx.x;
  const int w    = tid >> 6;
  const int lane = tid & 63;
  const int colf = lane & 15;
  const int ksub = lane >> 4;
  const int rloc = lane & 7;

  unsigned* myflag = flagsF + bc * 32 + jc;          // producer heartbeat
  const unsigned* fpoll = flagsF + bc * 32 + w * 4;  // wave w's 4 producers (16B)

  // ---- publish my physical XCD id (hint table) ----
  unsigned my_xcc;
  asm volatile("s_getreg_b32 %0, hwreg(HW_REG_XCC_ID)" : "=s"(my_xcc));
  my_xcc &= 0xffu;
  if (tid == 0) {
    unsigned* tp = xcctab + wg;
    const unsigned v = 0x100u | my_xcc;
    asm volatile("global_store_dword %0, %1, off sc1" :: "v"(tp), "v"(v) : "memory");
  }

  // ---- one-time small LDS ----
  if (tid < 80) bm_s[tid] = bm[(tid % 5) * 512 + j0 + tid / 5];
  if (tid >= 128 && tid < 224) {
    const int c = tid - 128;
    bi_s[c] = bi[(c % 6) * 512 + j0 + c / 6];
  }
  // ---- init own hf/hs, publish State(0) with tag=1 (both copies) ----
  if (tid < 128) {
    const int r = tid >> 4, j16 = tid & 15;
    const float f = h0[(size_t)(r0 + r) * 512 + j0 + j16];
    const float s = h0[(size_t)32768 + (size_t)(r0 + r) * 512 + j0 + j16];
    hf_own[tid] = f;
    hs_own[tid] = s;
    const unsigned hb = f2bf_bits(f);
    const unsigned lb = f2bf_bits(f - bfbits2f(hb));
    u32x2 pr; pr[0] = hb | (lb << 16); pr[1] = 1u;
    const size_t eo = (size_t)(r0 + r) * 512 + j0 + j16;
    asm volatile("global_store_dwordx2 %0, %1, off"     :: "v"(stateFA + eo), "v"(pr) : "memory");
    asm volatile("global_store_dwordx2 %0, %1, off sc1" :: "v"(stateSA + eo), "v"(pr) : "memory");
  }
  if (tid == 0) {
    const unsigned one = 1u;
    asm volatile("global_store_dword %0, %1, off" :: "v"(myflag), "v"(one) : "memory");
  }

  // ---- per-wave locality gate: are my 4 producers on my XCD? ----
  bool fastmode;
  {
    unsigned pv = 0x100u | my_xcc;   // lanes >= 4: trivially equal
    if (lane < 4) {
      const unsigned* tp = xcctab + bc + (w * 4 + lane) * 8;
      for (;;) {
        unsigned v;
        asm volatile("global_load_dword %0, %1, off sc1" : "=&v"(v) : "v"(tp) : "memory");
        asm volatile("s_waitcnt vmcnt(0)" ::: "memory");
        __builtin_amdgcn_sched_barrier(0);
        if (v & 0x100u) { pv = v; break; }
        __builtin_amdgcn_s_sleep(1);
      }
    }
    fastmode = __all((pv & 0xffu) == my_xcc);
  }

  // ---- B-fragment gathers ----
  short8 bh[5][2], bl[5][2];
  #pragma unroll
  for (int nt = 0; nt < 5; ++nt) {
    const int c = nt * 16 + colf;
    const int gcol = (c % 5) * 512 + j0 + c / 5;
    #pragma unroll
    for (int kt = 0; kt < 2; ++kt) {
      #pragma unroll
      for (int j = 0; j < 8; ++j) {
        const int kg = w * 64 + kt * 32 + ksub * 8 + j;
        const float wv = Wm[(size_t)kg * 2560 + gcol];
        const unsigned hb = f2bf_bits(wv);
        bh[nt][kt][j] = (short)hb;
        bl[nt][kt][j] = (short)f2bf_bits(wv - bfbits2f(hb));
      }
    }
  }
  const int iekc = w & 3;
  const int ienh = w >> 2;
  short8 bih[3], bil[3];
  #pragma unroll
  for (int nt = 0; nt < 3; ++nt) {
    const int c = (ienh * 3 + nt) * 16 + colf;
    const int gcol = (c % 6) * 512 + j0 + c / 6;
    #pragma unroll
    for (int j = 0; j < 8; ++j) {
      const int kg = iekc * 32 + ksub * 8 + j;
      const float wv = Wi[(size_t)kg * 3072 + gcol];
      const unsigned hb = f2bf_bits(wv);
      bih[nt][j] = (short)hb;
      bil[nt][j] = (short)f2bf_bits(wv - bfbits2f(hb));
    }
  }

  const float* ubase = u + (size_t)(r0 + rloc) * 131072 + iekc * 32 + ksub * 8;

  // ---- ie math from prefetched registers ----
  auto ie_math = [&](float4 xa_, float4 xb_) {
    const float xv[8] = {xa_.x, xa_.y, xa_.z, xa_.w, xb_.x, xb_.y, xb_.z, xb_.w};
    short8 ah, al;
    #pragma unroll
    for (int j = 0; j < 8; ++j) {
      const unsigned hb = f2bf_bits(xv[j]);
      ah[j] = (short)hb;
      al[j] = (short)f2bf_bits(xv[j] - bfbits2f(hb));
    }
    f32x4 acc[3];
    #pragma unroll
    for (int nt = 0; nt < 3; ++nt) { acc[nt][0]=0.f; acc[nt][1]=0.f; acc[nt][2]=0.f; acc[nt][3]=0.f; }
    #pragma unroll
    for (int nt = 0; nt < 3; ++nt) {
      acc[nt] = __builtin_amdgcn_mfma_f32_16x16x32_bf16(ah, bih[nt], acc[nt], 0, 0, 0);
      acc[nt] = __builtin_amdgcn_mfma_f32_16x16x32_bf16(ah, bil[nt], acc[nt], 0, 0, 0);
      acc[nt] = __builtin_amdgcn_mfma_f32_16x16x32_bf16(al, bih[nt], acc[nt], 0, 0, 0);
    }
    if (lane < 32) {
      const int rb = (lane >> 4) * 4;
      #pragma unroll
      for (int nt = 0; nt < 3; ++nt)
        #pragma unroll
        for (int i = 0; i < 4; ++i)
          ie_part[iekc * 768 + (rb + i) * 96 + (ienh * 3 + nt) * 16 + colf] = acc[nt][i];
    }
  };

  // ---- ie(0) ----
  {
    const float4 xa0 = *(const float4*)ubase;
    const float4 xb0 = *(const float4*)(ubase + 4);
    ie_math(xa0, xb0);
  }

  const bool active = (lane & 8) == 0;   // fragment rows 8-15 are padding

  for (int st = 0; st < LSTEP; ++st) {
    const unsigned long long* __restrict__ scurF = (st & 1) ? stateFB : stateFA;
    unsigned long long* __restrict__ snxtF       = (st & 1) ? stateFA : stateFB;
    const unsigned long long* __restrict__ scurS = (st & 1) ? stateSB : stateSA;
    unsigned long long* __restrict__ snxtS       = (st & 1) ? stateSA : stateSB;

    // ======== phase 1: flag-gated poll-with-payload, unpack, MFMA ========
    {
      const unsigned tag = (unsigned)(st + 1);
      const size_t eoff = (size_t)(r0 + rloc) * 512 + w * 64 + ksub * 8;
      u32x4 p0 = {0,0,0,0}, p1 = {0,0,0,0}, p2 = {0,0,0,0}, p3 = {0,0,0,0};
      u32x4 p4 = {0,0,0,0}, p5 = {0,0,0,0}, p6 = {0,0,0,0}, p7 = {0,0,0,0};
      if (active) {
#define READ8(PTR, FLAG, OKVAR)                                                                              \
        {                                                                                                    \
          asm volatile("global_load_dwordx4 %0, %1, off " FLAG            : "=&v"(p0) : "v"(PTR) : "memory"); \
          asm volatile("global_load_dwordx4 %0, %1, off offset:16 " FLAG  : "=&v"(p1) : "v"(PTR) : "memory"); \
          asm volatile("global_load_dwordx4 %0, %1, off offset:32 " FLAG  : "=&v"(p2) : "v"(PTR) : "memory"); \
          asm volatile("global_load_dwordx4 %0, %1, off offset:48 " FLAG  : "=&v"(p3) : "v"(PTR) : "memory"); \
          asm volatile("global_load_dwordx4 %0, %1, off offset:256 " FLAG : "=&v"(p4) : "v"(PTR) : "memory"); \
          asm volatile("global_load_dwordx4 %0, %1, off offset:272 " FLAG : "=&v"(p5) : "v"(PTR) : "memory"); \
          asm volatile("global_load_dwordx4 %0, %1, off offset:288 " FLAG : "=&v"(p6) : "v"(PTR) : "memory"); \
          asm volatile("global_load_dwordx4 %0, %1, off offset:304 " FLAG : "=&v"(p7) : "v"(PTR) : "memory"); \
          asm volatile("s_waitcnt vmcnt(0)" ::: "memory");                                                   \
          __builtin_amdgcn_sched_barrier(0);  /* rule #18: compare AFTER waitcnt */                          \
          OKVAR = p0[1] >= tag && p0[3] >= tag && p1[1] >= tag && p1[3] >= tag                               \
               && p2[1] >= tag && p2[3] >= tag && p3[1] >= tag && p3[3] >= tag                               \
               && p4[1] >= tag && p4[3] >= tag && p5[1] >= tag && p5[3] >= tag                               \
               && p6[1] >= tag && p6[3] >= tag && p7[1] >= tag && p7[3] >= tag;                              \
        }
        bool got = false;
        if (fastmode) {
          const unsigned long long* baseF = scurF + eoff;
          bool ok;
          READ8(baseF, "nt", ok)            // hot path: first try reads payload
          if (__all(ok)) {
            got = true;
          } else {
            // retry loop: 16B flag hint (1 broadcast L2 access) before any
            // payload re-read — kills the 4KB/attempt L2-BW congestion.
            int tries = 0;
            do {
              __builtin_amdgcn_s_sleep(1);
              u32x4 fl;
              asm volatile("global_load_dwordx4 %0, %1, off nt"
                           : "=&v"(fl) : "v"(fpoll) : "memory");
              asm volatile("s_waitcnt vmcnt(0)" ::: "memory");
              __builtin_amdgcn_sched_barrier(0);
              const bool fok = fl[0] >= tag && fl[1] >= tag && fl[2] >= tag && fl[3] >= tag;
              if (__all(fok)) {
                READ8(baseF, "nt", ok)
                if (__all(ok)) { got = true; break; }
              }
            } while (++tries < FAST_TRIES);
            if (!got) fastmode = false;     // permanent demotion — no deadlock
          }
        }
        if (!got) {
          const unsigned long long* baseS = scurS + eoff;
          for (;;) {
            bool ok;
            READ8(baseS, "sc1", ok)
            if (__all(ok)) break;
            __builtin_amdgcn_s_sleep(1);
          }
        }
#undef READ8
      }
      __builtin_amdgcn_sched_barrier(0);
      short8 ah[2], al[2];
      ah[0][0] = (short)(p0[0] & 0xffffu); al[0][0] = (short)(p0[0] >> 16);
      ah[0][1] = (short)(p0[2] & 0xffffu); al[0][1] = (short)(p0[2] >> 16);
      ah[0][2] = (short)(p1[0] & 0xffffu); al[0][2] = (short)(p1[0] >> 16);
      ah[0][3] = (short)(p1[2] & 0xffffu); al[0][3] = (short)(p1[2] >> 16);
      ah[0][4] = (short)(p2[0] & 0xffffu); al[0][4] = (short)(p2[0] >> 16);
      ah[0][5] = (short)(p2[2] & 0xffffu); al[0][5] = (short)(p2[2] >> 16);
      ah[0][6] = (short)(p3[0] & 0xffffu); al[0][6] = (short)(p3[0] >> 16);
      ah[0][7] = (short)(p3[2] & 0xffffu); al[0][7] = (short)(p3[2] >> 16);
      ah[1][0] = (short)(p4[0] & 0xffffu); al[1][0] = (short)(p4[0] >> 16);
      ah[1][1] = (short)(p4[2] & 0xffffu); al[1][1] = (short)(p4[2] >> 16);
      ah[1][2] = (short)(p5[0] & 0xffffu); al[1][2] = (short)(p5[0] >> 16);
      ah[1][3] = (short)(p5[2] & 0xffffu); al[1][3] = (short)(p5[2] >> 16);
      ah[1][4] = (short)(p6[0] & 0xffffu); al[1][4] = (short)(p6[0] >> 16);
      ah[1][5] = (short)(p6[2] & 0xffffu); al[1][5] = (short)(p6[2] >> 16);
      ah[1][6] = (short)(p7[0] & 0xffffu); al[1][6] = (short)(p7[0] >> 16);
      ah[1][7] = (short)(p7[2] & 0xffffu); al[1][7] = (short)(p7[2] >> 16);
      f32x4 acc[5];
      #pragma unroll
      for (int nt = 0; nt < 5; ++nt) { acc[nt][0]=0.f; acc[nt][1]=0.f; acc[nt][2]=0.f; acc[nt][3]=0.f; }
      #pragma unroll
      for (int nt = 0; nt < 5; ++nt)
        #pragma unroll
        for (int kt = 0; kt < 2; ++kt) {
          acc[nt] = __builtin_amdgcn_mfma_f32_16x16x32_bf16(ah[kt], bh[nt][kt], acc[nt], 0, 0, 0);
          acc[nt] = __builtin_amdgcn_mfma_f32_16x16x32_bf16(ah[kt], bl[nt][kt], acc[nt], 0, 0, 0);
          acc[nt] = __builtin_amdgcn_mfma_f32_16x16x32_bf16(al[kt], bh[nt][kt], acc[nt], 0, 0, 0);
        }
      if (lane < 32) {
        const int rb = (lane >> 4) * 4;
        #pragma unroll
        for (int nt = 0; nt < 5; ++nt)
          #pragma unroll
          for (int i = 0; i < 4; ++i)
            part_s[(w * 8 + rb + i) * 80 + nt * 16 + colf] = acc[nt][i];
      }
    }
    __syncthreads();   // sync #1 — part_s/ie_part complete for step st

    // ---- prefetch u(st+1) ----
    float4 xa = {0.f, 0.f, 0.f, 0.f}, xb = {0.f, 0.f, 0.f, 0.f};
    if (st + 1 < LSTEP) {
      const float* up = ubase + (size_t)(st + 1) * 128;
      xa = *(const float4*)up;
      xb = *(const float4*)(up + 4);
    }

    // ======== phase 2: fused reduce + gates + dual tagged publish ========
    if (tid < 128) {
      const int r = tid >> 4, j16 = tid & 15;
      float m[5];
      #pragma unroll
      for (int g = 0; g < 5; ++g) {
        float v = bm_s[j16 * 5 + g];
        #pragma unroll
        for (int kh = 0; kh < 8; ++kh) v += part_s[kh * 640 + r * 80 + j16 * 5 + g];
        m[g] = v;
      }
      float iacc[6];
      #pragma unroll
      for (int g = 0; g < 6; ++g) {
        float v = bi_s[j16 * 6 + g];
        #pragma unroll
        for (int kc = 0; kc < 4; ++kc) v += ie_part[kc * 768 + r * 96 + j16 * 6 + g];
        iacc[g] = v;
      }
      const float hf = hf_own[tid];
      const float hs = hs_own[tid];
      const float a = 1.f + ftanh(iacc[0] + m[0]);
      const float b = 1.5f * (1.f + ftanh(iacc[1] + m[1]));
      const float c = 0.3f + 0.7f * fsig(iacc[2] + m[2]);
      const float d = 0.03f * fsig(iacc[3] + m[3]);
      const float e = 1.f + fsig(iacc[4] + m[4]);
      const float hfn_v = (1.f - c) * hf + c * ftanh(iacc[5] + (a + b * hf * hf - hs) * hf);
      const float eh  = e * hf;
      const float eh2 = eh * eh;
      const float hsn_v = hs * (1.f - d) + d * eh2 * eh2;
      hf_own[tid] = hfn_v;
      hs_own[tid] = hsn_v;
      const unsigned hb = f2bf_bits(hfn_v);
      const unsigned lb = f2bf_bits(hfn_v - bfbits2f(hb));
      u32x2 pr; pr[0] = hb | (lb << 16); pr[1] = (unsigned)(st + 2);
      const size_t eo = (size_t)(r0 + r) * 512 + j0 + j16;
      asm volatile("global_store_dwordx2 %0, %1, off"     :: "v"(snxtF + eo), "v"(pr) : "memory");
      asm volatile("global_store_dwordx2 %0, %1, off sc1" :: "v"(snxtS + eo), "v"(pr) : "memory");
      out[(size_t)(r0 + r) * 524288 + (size_t)st * 512 + j0 + j16] = hfn_v;
      if (st == LSTEP - 1)
        out[(size_t)33554432 + (size_t)(r0 + r) * 512 + j0 + j16] = hfn_v;
    }
    __syncthreads();   // sync #2 — part_s/ie_part free for reuse
    // heartbeat hint (plain store; tags remain the correctness gate)
    if (tid == 0) {
      const unsigned v = (unsigned)(st + 2);
      asm volatile("global_store_dword %0, %1, off" :: "v"(myflag), "v"(v) : "memory");
    }
    if (st + 1 < LSTEP) ie_math(xa, xb);  // KEPT: publish->poll delay (R17/R18 lesson)
  }
}

extern "C" void kernel_launch(void* const* d_in, const int* in_sizes, int n_in,
                              void* d_out, int out_size, void* d_ws, size_t ws_size,
                              hipStream_t stream) {
  (void)in_sizes; (void)n_in; (void)out_size; (void)ws_size;
  const float* u  = (const float*)d_in[0];
  const float* h0 = (const float*)d_in[1];
  const float* Wi = (const float*)d_in[2];
  const float* bi = (const float*)d_in[3];
  const float* Wm = (const float*)d_in[4];
  const float* bm = (const float*)d_in[5];
  float* out = (float*)d_out;
  unsigned* xcctab = (unsigned*)d_ws;                        // [0, 1024)
  unsigned* flagsF = (unsigned*)((char*)d_ws + 1024);        // [1024, 2048)
  char* sb = (char*)d_ws + 4096;
  unsigned long long* stateFA = (unsigned long long*)(sb);
  unsigned long long* stateFB = (unsigned long long*)(sb + 262144);
  unsigned long long* stateSA = (unsigned long long*)(sb + 2 * 262144);
  unsigned long long* stateSB = (unsigned long long*)(sb + 3 * 262144);
  hipMemsetAsync(d_ws, 0, 4096 + 4 * 262144, stream);  // xcctab+flags+all tags
  hipLaunchKernelGGL(fused_scan, dim3(NWG), dim3(NTH), 0, stream,
                     u, h0, Wi, bi, Wm, bm, out,
                     stateFA, stateFB, stateSA, stateSB, xcctab, flagsF);
}